// Round 15
// baseline (301.381 us; speedup 1.0000x reference)
//
#include <hip/hip_runtime.h>

#define HID 256
#define NSEQ 1024
#define NH 16
#define DH 4
#define NB 4
#define SCALEF 0.5f
#define HEADSZ (NB * NH * NSEQ * DH)   // 262144 floats per projection buffer

typedef float f4 __attribute__((ext_vector_type(4)));

__device__ __forceinline__ float rfl(float x) {
    return __builtin_bit_cast(float,
        __builtin_amdgcn_readfirstlane(__builtin_bit_cast(int, x)));
}

#define LOG2E 1.44269504f
#define EOFF  (-16.f * LOG2E)

// ---------------------------------------------------------------------------
// Kernel 1: 1x1-conv projections (unchanged from R12).
// ---------------------------------------------------------------------------
__global__ __launch_bounds__(256) void proj_kernel(
    const float* __restrict__ q, const float* __restrict__ k,
    const float* __restrict__ v, const float* __restrict__ Wq,
    const float* __restrict__ Wk, const float* __restrict__ Wv,
    float* __restrict__ ws)
{
    const int tid   = threadIdx.x;
    const int pos_l = tid & 63;
    int cb = __builtin_amdgcn_readfirstlane(tid >> 6);
    const int p    = blockIdx.y;
    const int b    = blockIdx.z;
    const int pos0 = blockIdx.x * 64;

    const float* in = (p == 0) ? q : (p == 1) ? k : v;
    const float* W  = (p == 0) ? Wq : (p == 1) ? Wk : Wv;
    float* dst = ws + (size_t)p * HEADSZ;

    __shared__ float lds_in[64][64];

    const int row_l = tid >> 4;
    const int col4  = tid & 15;
    const float* inb = in + (size_t)b * HID * NSEQ + pos0;

    float acc[16];
#pragma unroll
    for (int j = 0; j < 16; ++j) acc[j] = 0.f;

    f4 vbuf[4];
#pragma unroll
    for (int t = 0; t < 4; ++t)
        vbuf[t] = *(const f4*)(inb + (size_t)(row_l + 16 * t) * NSEQ + col4 * 4);

    for (int c = 0; c < 4; ++c) {
#pragma unroll
        for (int t = 0; t < 4; ++t)
            *(f4*)&lds_in[row_l + 16 * t][col4 * 4] = vbuf[t];
        __syncthreads();
        if (c < 3) {
#pragma unroll
            for (int t = 0; t < 4; ++t)
                vbuf[t] = *(const f4*)(inb +
                    (size_t)((c + 1) * 64 + row_l + 16 * t) * NSEQ + col4 * 4);
        }
#pragma unroll
        for (int i8 = 0; i8 < 64; i8 += 8) {
            float x[8];
#pragma unroll
            for (int j = 0; j < 8; ++j) x[j] = lds_in[i8 + j][pos_l];
#pragma unroll
            for (int kk = 0; kk < 16; ++kk) {
                const float* wr = W + (cb * 16 + kk) * HID + c * 64 + i8;
#pragma unroll
                for (int j = 0; j < 8; ++j)
                    acc[kk] = fmaf(wr[j], x[j], acc[kk]);
            }
        }
        __syncthreads();
    }

    const int pos_g = pos0 + pos_l;
    const int h     = pos_g & 15;
    const int nsub  = pos_g >> 4;
#pragma unroll
    for (int kk = 0; kk < 16; ++kk) {
        int c = cb * 16 + kk;
        int d = c >> 4;
        int n = (c & 15) * 64 + nsub;
        dst[(((size_t)b * NH + h) * NSEQ + n) * DH + d] = acc[kk];
    }
}

// ---------------------------------------------------------------------------
// Kernel 2: attention — ROW-SEQUENTIAL bias (each wave streams whole 4KB
// rows, block covers 128KB contiguous; one DRAM-row visit instead of R12's
// 4 strided quarter-visits) + LDS-staged K/V with the CONFLICT-FREE
// interleaved map (key = c*256 + i*64 + lane: 16B/lane consecutive
// ds_read_b128; R14 measured 3.1M conflicts for the 64B/lane map).
// Per-row scalar accumulators (rule #20), immediate 6-step butterfly,
// static-select write. launch_bounds(256,5): 5 blocks/CU (LDS-capped),
// 20 waves/CU.
// ---------------------------------------------------------------------------
__global__ __launch_bounds__(256, 5) void attn_kernel(
    const float* __restrict__ bias, const float* __restrict__ ws,
    float* __restrict__ x2)
{
    const int tid  = threadIdx.x;
    const int lane = tid & 63;
    const int wave = tid >> 6;
    const int h    = blockIdx.y;
    const int b    = blockIdx.z;
    const int n0   = blockIdx.x * 32 + wave * 8;   // this wave's 8 query rows

    const float4* Qh = (const float4*)(ws);
    const float4* Kh = (const float4*)(ws + (size_t)1 * HEADSZ);
    const float4* Vh = (const float4*)(ws + (size_t)2 * HEADSZ);
    const int headbase = (b * NH + h) * NSEQ;

    __shared__ float4 ldsK[NSEQ];   // 16 KB
    __shared__ float4 ldsV[NSEQ];   // 16 KB

#pragma unroll
    for (int t = 0; t < 4; ++t) {
        ldsK[tid + 256 * t] = Kh[headbase + tid + 256 * t];
        ldsV[tid + 256 * t] = Vh[headbase + tid + 256 * t];
    }
    __syncthreads();

#pragma unroll 1
    for (int r = 0; r < 8; ++r) {
        const int n = n0 + r;
        float4 qt = Qh[headbase + n];
        const float qx = rfl(qt.x), qy = rfl(qt.y),
                    qz = rfl(qt.z), qw = rfl(qt.w);
        const float* brow = bias + ((size_t)headbase + n) * NSEQ + lane * 4;

        // whole 4KB bias row, sequential: 4 x 1KB contiguous wave-loads
        f4 bb[4];
#pragma unroll
        for (int c = 0; c < 4; ++c)
            bb[c] = __builtin_nontemporal_load((const f4*)(brow + c * 256));

        float sum = 0.f, o0 = 0.f, o1 = 0.f, o2 = 0.f, o3 = 0.f;
#pragma unroll
        for (int c = 0; c < 4; ++c) {
#pragma unroll
            for (int i = 0; i < 4; ++i) {
                // conflict-free: consecutive 16B per lane
                float4 kb = ldsK[c * 256 + i * 64 + lane];
                float4 vb = ldsV[c * 256 + i * 64 + lane];
                float dot = qx * kb.x + qy * kb.y + qz * kb.z + qw * kb.w;
                // lane's key for (c,i) is c*256+i*64+lane; bias element for
                // that key lives at brow[c*256 + i*64 + lane] -> bb[c][i]?
                // bb[c] = brow[c*256 + lane*4 .. +3] covers keys c*256+lane*4+i
                // MISMATCH -> use matching map below instead.
                (void)dot;
            }
        }
        // --- matched-map version (keys = c*256 + lane*4 + i for bias f4;
        //     LDS read uses the same key index; 64B/lane ds_read accepted:
        //     measured cost ~5us total, bias order is the variable under test)
        sum = 0.f; o0 = o1 = o2 = o3 = 0.f;
#pragma unroll
        for (int c = 0; c < 4; ++c) {
#pragma unroll
            for (int i = 0; i < 4; ++i) {
                float4 kb = ldsK[c * 256 + lane * 4 + i];
                float4 vb = ldsV[c * 256 + lane * 4 + i];
                float dot = qx * kb.x + qy * kb.y + qz * kb.z + qw * kb.w;
                float s = fmaf(dot, SCALEF, bb[c][i]);
                float e = exp2f(fmaf(s, LOG2E, EOFF));   // exp(s-16)
                sum += e;
                o0 = fmaf(e, vb.x, o0);
                o1 = fmaf(e, vb.y, o1);
                o2 = fmaf(e, vb.z, o2);
                o3 = fmaf(e, vb.w, o3);
            }
        }

#pragma unroll
        for (int st = 1; st < 64; st <<= 1) {
            sum += __shfl_xor(sum, st, 64);
            o0  += __shfl_xor(o0,  st, 64);
            o1  += __shfl_xor(o1,  st, 64);
            o2  += __shfl_xor(o2,  st, 64);
            o3  += __shfl_xor(o3,  st, 64);
        }
        float val = (lane == 0) ? o0 : (lane == 1) ? o1 : (lane == 2) ? o2 : o3;
        if (lane < 4)
            x2[((size_t)b * (NH * DH) + h * DH + lane) * NSEQ + n] = val / sum;
    }
}

// ---------------------------------------------------------------------------
// Kernel 3: output 1x1 conv + BN(eval) + LeakyReLU (unchanged from R12).
// ---------------------------------------------------------------------------
__global__ __launch_bounds__(256) void out_kernel(
    const float* __restrict__ x2, const float* __restrict__ Wo,
    const float* __restrict__ bo, const float* __restrict__ gamma,
    const float* __restrict__ beta, const float* __restrict__ rmean,
    const float* __restrict__ rvar, float* __restrict__ out)
{
    const int pos4 = threadIdx.x * 4;
    const int o0   = blockIdx.y * 4;
    const int b    = blockIdx.z;

    const float* xb = x2 + (size_t)b * (NH * DH) * NSEQ;

    f4 acc[4];
#pragma unroll
    for (int j = 0; j < 4; ++j) acc[j] = (f4)(0.f);

#pragma unroll 8
    for (int c = 0; c < NH * DH; ++c) {
        f4 x = *(const f4*)(xb + (size_t)c * NSEQ + pos4);
#pragma unroll
        for (int j = 0; j < 4; ++j)
            acc[j] += Wo[(o0 + j) * (NH * DH) + c] * x;
    }
#pragma unroll
    for (int j = 0; j < 4; ++j) {
        int oc = o0 + j;
        float scale = gamma[oc] * rsqrtf(rvar[oc] + 1e-5f);
        f4 y = (acc[j] + (bo[oc] - rmean[oc])) * scale + beta[oc];
        float* dst = out + ((size_t)b * HID + oc) * NSEQ + pos4;
        f4 res;
#pragma unroll
        for (int d = 0; d < 4; ++d) {
            float yy = y[d];
            res[d] = (yy > 0.f) ? yy : 0.2f * yy;
        }
        *(f4*)dst = res;
    }
}

extern "C" void kernel_launch(void* const* d_in, const int* in_sizes, int n_in,
                              void* d_out, int out_size, void* d_ws, size_t ws_size,
                              hipStream_t stream) {
    const float* q     = (const float*)d_in[0];
    const float* k     = (const float*)d_in[1];
    const float* v     = (const float*)d_in[2];
    const float* bias  = (const float*)d_in[3];
    const float* Wq    = (const float*)d_in[4];
    const float* Wk    = (const float*)d_in[5];
    const float* Wv    = (const float*)d_in[6];
    const float* Wo    = (const float*)d_in[7];
    const float* bo    = (const float*)d_in[8];
    const float* gamma = (const float*)d_in[9];
    const float* beta  = (const float*)d_in[10];
    const float* rmean = (const float*)d_in[11];
    const float* rvar  = (const float*)d_in[12];

    float* ws = (float*)d_ws;
    float* x2 = ws + (size_t)3 * HEADSZ;
    float* out = (float*)d_out;

    proj_kernel<<<dim3(NSEQ / 64, 3, NB), 256, 0, stream>>>(q, k, v, Wq, Wk, Wv, ws);
    attn_kernel<<<dim3(NSEQ / 32, NH, NB), 256, 0, stream>>>(bias, ws, x2);
    out_kernel<<<dim3(1, HID / 4, NB), 256, 0, stream>>>(
        x2, Wo, bo, gamma, beta, rmean, rvar, out);
}

// Round 16
// 116.009 us; speedup vs baseline: 2.5979x; 2.5979x over previous
//
#include <hip/hip_runtime.h>

#define HID 256
#define NSEQ 1024
#define NH 16
#define DH 4
#define NB 4
#define SCALEF 0.5f
#define HEADSZ (NB * NH * NSEQ * DH)   // 262144 floats per projection buffer

typedef float f4 __attribute__((ext_vector_type(4)));

__device__ __forceinline__ float rfl(float x) {
    return __builtin_bit_cast(float,
        __builtin_amdgcn_readfirstlane(__builtin_bit_cast(int, x)));
}

#define LOG2E 1.44269504f
#define EOFF  (-16.f * LOG2E)

// ---------------------------------------------------------------------------
// Kernel 1: 1x1-conv projections (unchanged from R12).
// ---------------------------------------------------------------------------
__global__ __launch_bounds__(256) void proj_kernel(
    const float* __restrict__ q, const float* __restrict__ k,
    const float* __restrict__ v, const float* __restrict__ Wq,
    const float* __restrict__ Wk, const float* __restrict__ Wv,
    float* __restrict__ ws)
{
    const int tid   = threadIdx.x;
    const int pos_l = tid & 63;
    int cb = __builtin_amdgcn_readfirstlane(tid >> 6);
    const int p    = blockIdx.y;
    const int b    = blockIdx.z;
    const int pos0 = blockIdx.x * 64;

    const float* in = (p == 0) ? q : (p == 1) ? k : v;
    const float* W  = (p == 0) ? Wq : (p == 1) ? Wk : Wv;
    float* dst = ws + (size_t)p * HEADSZ;

    __shared__ float lds_in[64][64];

    const int row_l = tid >> 4;
    const int col4  = tid & 15;
    const float* inb = in + (size_t)b * HID * NSEQ + pos0;

    float acc[16];
#pragma unroll
    for (int j = 0; j < 16; ++j) acc[j] = 0.f;

    f4 vbuf[4];
#pragma unroll
    for (int t = 0; t < 4; ++t)
        vbuf[t] = *(const f4*)(inb + (size_t)(row_l + 16 * t) * NSEQ + col4 * 4);

    for (int c = 0; c < 4; ++c) {
#pragma unroll
        for (int t = 0; t < 4; ++t)
            *(f4*)&lds_in[row_l + 16 * t][col4 * 4] = vbuf[t];
        __syncthreads();
        if (c < 3) {
#pragma unroll
            for (int t = 0; t < 4; ++t)
                vbuf[t] = *(const f4*)(inb +
                    (size_t)((c + 1) * 64 + row_l + 16 * t) * NSEQ + col4 * 4);
        }
#pragma unroll
        for (int i8 = 0; i8 < 64; i8 += 8) {
            float x[8];
#pragma unroll
            for (int j = 0; j < 8; ++j) x[j] = lds_in[i8 + j][pos_l];
#pragma unroll
            for (int kk = 0; kk < 16; ++kk) {
                const float* wr = W + (cb * 16 + kk) * HID + c * 64 + i8;
#pragma unroll
                for (int j = 0; j < 8; ++j)
                    acc[kk] = fmaf(wr[j], x[j], acc[kk]);
            }
        }
        __syncthreads();
    }

    const int pos_g = pos0 + pos_l;
    const int h     = pos_g & 15;
    const int nsub  = pos_g >> 4;
#pragma unroll
    for (int kk = 0; kk < 16; ++kk) {
        int c = cb * 16 + kk;
        int d = c >> 4;
        int n = (c & 15) * 64 + nsub;
        dst[(((size_t)b * NH + h) * NSEQ + n) * DH + d] = acc[kk];
    }
}

// ---------------------------------------------------------------------------
// Kernel 2: attention — R12 structure with HALVED accumulator live-range.
// Wave's 8 rows processed as TWO sequential groups of 4: peak live state
// ~70 VGPR (20 acc + 32 K/V + bias + addr) < 128 cap -> no spill (R8/R12
// carried WRITE~100MB scratch at VGPR=64; R15's min-waves=5 made it fatal).
// All else identical to R12: LDS-staged K/V (contiguous map), f4 NT bias
// loads (1KB/instr), SGPR Q, static accumulators, 6-step butterfly,
// static-select write.
// ---------------------------------------------------------------------------
__global__ __launch_bounds__(256, 4) void attn_kernel(
    const float* __restrict__ bias, const float* __restrict__ ws,
    float* __restrict__ x2)
{
    const int tid  = threadIdx.x;
    const int lane = tid & 63;
    const int wave = tid >> 6;
    const int h    = blockIdx.y;
    const int b    = blockIdx.z;

    const float4* Qh = (const float4*)(ws);
    const float4* Kh = (const float4*)(ws + (size_t)1 * HEADSZ);
    const float4* Vh = (const float4*)(ws + (size_t)2 * HEADSZ);
    const int headbase = (b * NH + h) * NSEQ;
    const int mb = lane * 4;

    __shared__ float4 ldsK[NSEQ];   // 16 KB
    __shared__ float4 ldsV[NSEQ];   // 16 KB

#pragma unroll
    for (int t = 0; t < 4; ++t) {
        ldsK[tid + 256 * t] = Kh[headbase + tid + 256 * t];
        ldsV[tid + 256 * t] = Vh[headbase + tid + 256 * t];
    }
    __syncthreads();

#pragma unroll 1
    for (int g = 0; g < 2; ++g) {
        const int n0 = blockIdx.x * 32 + wave * 8 + g * 4;  // this group's 4 rows

        float qx[4], qy[4], qz[4], qw[4];
#pragma unroll
        for (int r = 0; r < 4; ++r) {
            float4 t = Qh[headbase + n0 + r];
            qx[r] = rfl(t.x); qy[r] = rfl(t.y);
            qz[r] = rfl(t.z); qw[r] = rfl(t.w);
        }

        float sum[4];
        float o[4][4];
#pragma unroll
        for (int r = 0; r < 4; ++r) {
            sum[r] = 0.f;
            o[r][0] = o[r][1] = o[r][2] = o[r][3] = 0.f;
        }

        const float* bwave = bias + ((size_t)headbase + n0) * NSEQ + mb;

#pragma unroll 1
        for (int c = 0; c < 4; ++c) {              // 4 chunks x 256 keys
            float4 kb[4], vb[4];
#pragma unroll
            for (int i = 0; i < 4; ++i) {
                kb[i] = ldsK[c * 256 + mb + i];
                vb[i] = ldsV[c * 256 + mb + i];
            }
#pragma unroll
            for (int r = 0; r < 4; ++r) {
                f4 bb = __builtin_nontemporal_load(
                    (const f4*)(bwave + (size_t)r * NSEQ + c * 256));
#pragma unroll
                for (int i = 0; i < 4; ++i) {
                    float dot = qx[r] * kb[i].x + qy[r] * kb[i].y +
                                qz[r] * kb[i].z + qw[r] * kb[i].w;
                    float s = fmaf(dot, SCALEF, bb[i]);
                    float e = exp2f(fmaf(s, LOG2E, EOFF));   // exp(s-16)
                    sum[r] += e;
                    o[r][0] = fmaf(e, vb[i].x, o[r][0]);
                    o[r][1] = fmaf(e, vb[i].y, o[r][1]);
                    o[r][2] = fmaf(e, vb[i].z, o[r][2]);
                    o[r][3] = fmaf(e, vb[i].w, o[r][3]);
                }
            }
        }

#pragma unroll
        for (int r = 0; r < 4; ++r) {
            float s = sum[r], a0 = o[r][0], a1 = o[r][1],
                  a2 = o[r][2], a3 = o[r][3];
#pragma unroll
            for (int st = 1; st < 64; st <<= 1) {
                s  += __shfl_xor(s,  st, 64);
                a0 += __shfl_xor(a0, st, 64);
                a1 += __shfl_xor(a1, st, 64);
                a2 += __shfl_xor(a2, st, 64);
                a3 += __shfl_xor(a3, st, 64);
            }
            float val = (lane == 0) ? a0 : (lane == 1) ? a1
                      : (lane == 2) ? a2 : a3;
            if (lane < 4)
                x2[((size_t)b * (NH * DH) + h * DH + lane) * NSEQ + n0 + r] =
                    val / s;
        }
    }
}

// ---------------------------------------------------------------------------
// Kernel 3: output 1x1 conv + BN(eval) + LeakyReLU (unchanged from R12).
// ---------------------------------------------------------------------------
__global__ __launch_bounds__(256) void out_kernel(
    const float* __restrict__ x2, const float* __restrict__ Wo,
    const float* __restrict__ bo, const float* __restrict__ gamma,
    const float* __restrict__ beta, const float* __restrict__ rmean,
    const float* __restrict__ rvar, float* __restrict__ out)
{
    const int pos4 = threadIdx.x * 4;
    const int o0   = blockIdx.y * 4;
    const int b    = blockIdx.z;

    const float* xb = x2 + (size_t)b * (NH * DH) * NSEQ;

    f4 acc[4];
#pragma unroll
    for (int j = 0; j < 4; ++j) acc[j] = (f4)(0.f);

#pragma unroll 8
    for (int c = 0; c < NH * DH; ++c) {
        f4 x = *(const f4*)(xb + (size_t)c * NSEQ + pos4);
#pragma unroll
        for (int j = 0; j < 4; ++j)
            acc[j] += Wo[(o0 + j) * (NH * DH) + c] * x;
    }
#pragma unroll
    for (int j = 0; j < 4; ++j) {
        int oc = o0 + j;
        float scale = gamma[oc] * rsqrtf(rvar[oc] + 1e-5f);
        f4 y = (acc[j] + (bo[oc] - rmean[oc])) * scale + beta[oc];
        float* dst = out + ((size_t)b * HID + oc) * NSEQ + pos4;
        f4 res;
#pragma unroll
        for (int d = 0; d < 4; ++d) {
            float yy = y[d];
            res[d] = (yy > 0.f) ? yy : 0.2f * yy;
        }
        *(f4*)dst = res;
    }
}

extern "C" void kernel_launch(void* const* d_in, const int* in_sizes, int n_in,
                              void* d_out, int out_size, void* d_ws, size_t ws_size,
                              hipStream_t stream) {
    const float* q     = (const float*)d_in[0];
    const float* k     = (const float*)d_in[1];
    const float* v     = (const float*)d_in[2];
    const float* bias  = (const float*)d_in[3];
    const float* Wq    = (const float*)d_in[4];
    const float* Wk    = (const float*)d_in[5];
    const float* Wv    = (const float*)d_in[6];
    const float* Wo    = (const float*)d_in[7];
    const float* bo    = (const float*)d_in[8];
    const float* gamma = (const float*)d_in[9];
    const float* beta  = (const float*)d_in[10];
    const float* rmean = (const float*)d_in[11];
    const float* rvar  = (const float*)d_in[12];

    float* ws = (float*)d_ws;
    float* x2 = ws + (size_t)3 * HEADSZ;
    float* out = (float*)d_out;

    proj_kernel<<<dim3(NSEQ / 64, 3, NB), 256, 0, stream>>>(q, k, v, Wq, Wk, Wv, ws);
    attn_kernel<<<dim3(NSEQ / 32, NH, NB), 256, 0, stream>>>(bias, ws, x2);
    out_kernel<<<dim3(1, HID / 4, NB), 256, 0, stream>>>(
        x2, Wo, bo, gamma, beta, rmean, rvar, out);
}

// Round 17
// 111.067 us; speedup vs baseline: 2.7135x; 1.0445x over previous
//
#include <hip/hip_runtime.h>

#define HID 256
#define NSEQ 1024
#define NH 16
#define DH 4
#define NB 4
#define SCALEF 0.5f
#define HEADSZ (NB * NH * NSEQ * DH)   // 262144 floats per projection buffer

typedef float f4 __attribute__((ext_vector_type(4)));

__device__ __forceinline__ float rfl(float x) {
    return __builtin_bit_cast(float,
        __builtin_amdgcn_readfirstlane(__builtin_bit_cast(int, x)));
}

#define LOG2E 1.44269504f
#define EOFF  (-16.f * LOG2E)

// ---------------------------------------------------------------------------
// Kernel 1: 1x1-conv projections (unchanged).
// ---------------------------------------------------------------------------
__global__ __launch_bounds__(256) void proj_kernel(
    const float* __restrict__ q, const float* __restrict__ k,
    const float* __restrict__ v, const float* __restrict__ Wq,
    const float* __restrict__ Wk, const float* __restrict__ Wv,
    float* __restrict__ ws)
{
    const int tid   = threadIdx.x;
    const int pos_l = tid & 63;
    int cb = __builtin_amdgcn_readfirstlane(tid >> 6);
    const int p    = blockIdx.y;
    const int b    = blockIdx.z;
    const int pos0 = blockIdx.x * 64;

    const float* in = (p == 0) ? q : (p == 1) ? k : v;
    const float* W  = (p == 0) ? Wq : (p == 1) ? Wk : Wv;
    float* dst = ws + (size_t)p * HEADSZ;

    __shared__ float lds_in[64][64];

    const int row_l = tid >> 4;
    const int col4  = tid & 15;
    const float* inb = in + (size_t)b * HID * NSEQ + pos0;

    float acc[16];
#pragma unroll
    for (int j = 0; j < 16; ++j) acc[j] = 0.f;

    f4 vbuf[4];
#pragma unroll
    for (int t = 0; t < 4; ++t)
        vbuf[t] = *(const f4*)(inb + (size_t)(row_l + 16 * t) * NSEQ + col4 * 4);

    for (int c = 0; c < 4; ++c) {
#pragma unroll
        for (int t = 0; t < 4; ++t)
            *(f4*)&lds_in[row_l + 16 * t][col4 * 4] = vbuf[t];
        __syncthreads();
        if (c < 3) {
#pragma unroll
            for (int t = 0; t < 4; ++t)
                vbuf[t] = *(const f4*)(inb +
                    (size_t)((c + 1) * 64 + row_l + 16 * t) * NSEQ + col4 * 4);
        }
#pragma unroll
        for (int i8 = 0; i8 < 64; i8 += 8) {
            float x[8];
#pragma unroll
            for (int j = 0; j < 8; ++j) x[j] = lds_in[i8 + j][pos_l];
#pragma unroll
            for (int kk = 0; kk < 16; ++kk) {
                const float* wr = W + (cb * 16 + kk) * HID + c * 64 + i8;
#pragma unroll
                for (int j = 0; j < 8; ++j)
                    acc[kk] = fmaf(wr[j], x[j], acc[kk]);
            }
        }
        __syncthreads();
    }

    const int pos_g = pos0 + pos_l;
    const int h     = pos_g & 15;
    const int nsub  = pos_g >> 4;
#pragma unroll
    for (int kk = 0; kk < 16; ++kk) {
        int c = cb * 16 + kk;
        int d = c >> 4;
        int n = (c & 15) * 64 + nsub;
        dst[(((size_t)b * NH + h) * NSEQ + n) * DH + d] = acc[kk];
    }
}

// ---------------------------------------------------------------------------
// Kernel 2: attention. Two changes vs R16 (both memory-supply-side):
//  (1) PLAIN loads for bias (no nontemporal hint): lets L2/L3 allocate the
//      bias stream; the 256MB Infinity Cache retains a large fraction across
//      graph replays (R14 measured FETCH=150MB < 256MB bias), serving it at
//      >HBM bandwidth.
//  (2) 64 rows per block (grid 16x16x4, still 4 blocks/CU = 16 waves/CU):
//      K/V staging traffic halves to 32MB aggregate.
// Structure otherwise identical to R16: 4-row register groups (no spill),
// LDS K/V contiguous map, SGPR Q, static accumulators, 6-step butterfly,
// static-select write.
// ---------------------------------------------------------------------------
__global__ __launch_bounds__(256, 4) void attn_kernel(
    const float* __restrict__ bias, const float* __restrict__ ws,
    float* __restrict__ x2)
{
    const int tid  = threadIdx.x;
    const int lane = tid & 63;
    const int wave = tid >> 6;
    const int h    = blockIdx.y;
    const int b    = blockIdx.z;

    const float4* Qh = (const float4*)(ws);
    const float4* Kh = (const float4*)(ws + (size_t)1 * HEADSZ);
    const float4* Vh = (const float4*)(ws + (size_t)2 * HEADSZ);
    const int headbase = (b * NH + h) * NSEQ;
    const int mb = lane * 4;

    __shared__ float4 ldsK[NSEQ];   // 16 KB
    __shared__ float4 ldsV[NSEQ];   // 16 KB

#pragma unroll
    for (int t = 0; t < 4; ++t) {
        ldsK[tid + 256 * t] = Kh[headbase + tid + 256 * t];
        ldsV[tid + 256 * t] = Vh[headbase + tid + 256 * t];
    }
    __syncthreads();

#pragma unroll 1
    for (int g = 0; g < 4; ++g) {                   // 4 groups x 4 rows = 16/wave
        const int n0 = blockIdx.x * 64 + wave * 16 + g * 4;

        float qx[4], qy[4], qz[4], qw[4];
#pragma unroll
        for (int r = 0; r < 4; ++r) {
            float4 t = Qh[headbase + n0 + r];
            qx[r] = rfl(t.x); qy[r] = rfl(t.y);
            qz[r] = rfl(t.z); qw[r] = rfl(t.w);
        }

        float sum[4];
        float o[4][4];
#pragma unroll
        for (int r = 0; r < 4; ++r) {
            sum[r] = 0.f;
            o[r][0] = o[r][1] = o[r][2] = o[r][3] = 0.f;
        }

        const float* bwave = bias + ((size_t)headbase + n0) * NSEQ + mb;

#pragma unroll 1
        for (int c = 0; c < 4; ++c) {              // 4 chunks x 256 keys
            float4 kb[4], vb[4];
#pragma unroll
            for (int i = 0; i < 4; ++i) {
                kb[i] = ldsK[c * 256 + mb + i];
                vb[i] = ldsV[c * 256 + mb + i];
            }
#pragma unroll
            for (int r = 0; r < 4; ++r) {
                f4 bb = *(const f4*)(bwave + (size_t)r * NSEQ + c * 256);
#pragma unroll
                for (int i = 0; i < 4; ++i) {
                    float dot = qx[r] * kb[i].x + qy[r] * kb[i].y +
                                qz[r] * kb[i].z + qw[r] * kb[i].w;
                    float s = fmaf(dot, SCALEF, bb[i]);
                    float e = exp2f(fmaf(s, LOG2E, EOFF));   // exp(s-16)
                    sum[r] += e;
                    o[r][0] = fmaf(e, vb[i].x, o[r][0]);
                    o[r][1] = fmaf(e, vb[i].y, o[r][1]);
                    o[r][2] = fmaf(e, vb[i].z, o[r][2]);
                    o[r][3] = fmaf(e, vb[i].w, o[r][3]);
                }
            }
        }

#pragma unroll
        for (int r = 0; r < 4; ++r) {
            float s = sum[r], a0 = o[r][0], a1 = o[r][1],
                  a2 = o[r][2], a3 = o[r][3];
#pragma unroll
            for (int st = 1; st < 64; st <<= 1) {
                s  += __shfl_xor(s,  st, 64);
                a0 += __shfl_xor(a0, st, 64);
                a1 += __shfl_xor(a1, st, 64);
                a2 += __shfl_xor(a2, st, 64);
                a3 += __shfl_xor(a3, st, 64);
            }
            float val = (lane == 0) ? a0 : (lane == 1) ? a1
                      : (lane == 2) ? a2 : a3;
            if (lane < 4)
                x2[((size_t)b * (NH * DH) + h * DH + lane) * NSEQ + n0 + r] =
                    val / s;
        }
    }
}

// ---------------------------------------------------------------------------
// Kernel 3: output 1x1 conv + BN(eval) + LeakyReLU (unchanged).
// ---------------------------------------------------------------------------
__global__ __launch_bounds__(256) void out_kernel(
    const float* __restrict__ x2, const float* __restrict__ Wo,
    const float* __restrict__ bo, const float* __restrict__ gamma,
    const float* __restrict__ beta, const float* __restrict__ rmean,
    const float* __restrict__ rvar, float* __restrict__ out)
{
    const int pos4 = threadIdx.x * 4;
    const int o0   = blockIdx.y * 4;
    const int b    = blockIdx.z;

    const float* xb = x2 + (size_t)b * (NH * DH) * NSEQ;

    f4 acc[4];
#pragma unroll
    for (int j = 0; j < 4; ++j) acc[j] = (f4)(0.f);

#pragma unroll 8
    for (int c = 0; c < NH * DH; ++c) {
        f4 x = *(const f4*)(xb + (size_t)c * NSEQ + pos4);
#pragma unroll
        for (int j = 0; j < 4; ++j)
            acc[j] += Wo[(o0 + j) * (NH * DH) + c] * x;
    }
#pragma unroll
    for (int j = 0; j < 4; ++j) {
        int oc = o0 + j;
        float scale = gamma[oc] * rsqrtf(rvar[oc] + 1e-5f);
        f4 y = (acc[j] + (bo[oc] - rmean[oc])) * scale + beta[oc];
        float* dst = out + ((size_t)b * HID + oc) * NSEQ + pos4;
        f4 res;
#pragma unroll
        for (int d = 0; d < 4; ++d) {
            float yy = y[d];
            res[d] = (yy > 0.f) ? yy : 0.2f * yy;
        }
        *(f4*)dst = res;
    }
}

extern "C" void kernel_launch(void* const* d_in, const int* in_sizes, int n_in,
                              void* d_out, int out_size, void* d_ws, size_t ws_size,
                              hipStream_t stream) {
    const float* q     = (const float*)d_in[0];
    const float* k     = (const float*)d_in[1];
    const float* v     = (const float*)d_in[2];
    const float* bias  = (const float*)d_in[3];
    const float* Wq    = (const float*)d_in[4];
    const float* Wk    = (const float*)d_in[5];
    const float* Wv    = (const float*)d_in[6];
    const float* Wo    = (const float*)d_in[7];
    const float* bo    = (const float*)d_in[8];
    const float* gamma = (const float*)d_in[9];
    const float* beta  = (const float*)d_in[10];
    const float* rmean = (const float*)d_in[11];
    const float* rvar  = (const float*)d_in[12];

    float* ws = (float*)d_ws;
    float* x2 = ws + (size_t)3 * HEADSZ;
    float* out = (float*)d_out;

    proj_kernel<<<dim3(NSEQ / 64, 3, NB), 256, 0, stream>>>(q, k, v, Wq, Wk, Wv, ws);
    attn_kernel<<<dim3(NSEQ / 64, NH, NB), 256, 0, stream>>>(bias, ws, x2);
    out_kernel<<<dim3(1, HID / 4, NB), 256, 0, stream>>>(
        x2, Wo, bo, gamma, beta, rmean, rvar, out);
}